// Round 2
// baseline (292.422 us; speedup 1.0000x reference)
//
#include <hip/hip_runtime.h>
#include <math.h>

#define BATCH 4096
#define SEQ_T 512
#define ISZ   4
#define HID   64
#define OSZ   40
#define RPB   16     // batch rows per chain (MFMA N)
#define NCH   2      // independent chains per block -> 2 waves/SIMD fill latency

typedef __attribute__((ext_vector_type(8))) _Float16     half8;
typedef __attribute__((ext_vector_type(2))) _Float16     half2v;
typedef __attribute__((ext_vector_type(4))) float        float4v;
typedef __attribute__((ext_vector_type(2))) unsigned int uint2v;

static __device__ __forceinline__ half2v pk_f16(float a, float b) {
    return __builtin_bit_cast(half2v, __builtin_amdgcn_cvt_pkrtz(a, b)); // v_cvt_pkrtz_f16_f32
}

// tanh(x) = 1 - 2/(exp2(x*2*log2e)+1); saturating, NaN-free
static __device__ __forceinline__ float fast_tanh(float x) {
    float e = __builtin_amdgcn_exp2f(x * 2.885390081777927f);
    return fmaf(-2.0f, __builtin_amdgcn_rcpf(e + 1.0f), 1.0f);
}

// LDS-only barrier: global x prefetches stay in flight across it (r1: neutral on
// its own at 1 wave/SIMD; kept because at 2 waves/SIMD a vmcnt(0) drain would
// couple the two chains' global-load queues).
#define LDS_BARRIER() asm volatile("s_waitcnt lgkmcnt(0)\n\ts_barrier" ::: "memory")

// 512 threads = 8 waves = TWO independent 16-batch RNN chains per block.
// Round-1 analysis: 1 wave/SIMD exposed ~500cy/step of pure dependency-chain
// latency (barrier->ds_read->mfma chain->tanh->ds_write->barrier). Two
// symmetric chains co-resident per SIMD interleave those chains: wall/step ~
// max(latency ~600, issue 2x300) instead of latency+issue serialized.
__global__ __launch_bounds__(512, 1)
void rnn_f16x2_kernel(const float* __restrict__ x,
                      const float* __restrict__ W_ih,
                      const float* __restrict__ W_hh,
                      const float* __restrict__ b_ih,
                      const float* __restrict__ b_hh,
                      const float* __restrict__ fc_W,
                      const float* __restrict__ fc_b,
                      float* __restrict__ out)
{
    // Per-chain h terms in B-fragment-native order:
    // hterm[ch][buf][tau][g][n][j] = h_tau[k=8g+j] for batch col n.
    // Reader lane(n,q): b128 at [tau][4c+q][n][0] -> banks (4n+d)%32, 2-way (free).
    // Writer lane(n,q) wave w: rows 16w+4q+r -> g=2w+(q>>1), j0=4(q&1): b64, 2-way.
    __shared__ __attribute__((aligned(16))) _Float16 hterm[NCH][2][2][8][16][8];
    __shared__ __attribute__((aligned(16))) float hf[NCH][16][68];

    const int tid  = threadIdx.x;
    const int ch   = tid >> 8;         // chain 0 / 1
    const int ctid = tid & 255;        // chain-local tid
    const int wv   = ctid >> 6;
    const int lane = ctid & 63;
    const int n    = lane & 15;        // A: row m; B/C/D: batch col n
    const int q    = lane >> 4;
    const int blk0 = blockIdx.x * (RPB * NCH) + ch * RPB;

    // h(0) = 0: zero both chains' buffers
    {
        unsigned int* p = (unsigned int*)hterm;
        #pragma unroll
        for (int i = tid; i < (int)(sizeof(hterm) / 4); i += 512) p[i] = 0u;
    }

    // ---- static A fragments: W_hh row 16wv+n, 2-term fp16 split, K-chunks c=0,1 ----
    half8 A10, A11, A20, A21;   // A1x = hi term, A2x = residual term
    {
        const float* wr = W_hh + (16 * wv + n) * HID;
        #pragma unroll
        for (int j = 0; j < 8; ++j) {
            float f0 = wr[     8 * q + j];
            float f1 = wr[32 + 8 * q + j];
            _Float16 h0 = (_Float16)f0; A10[j] = h0; A20[j] = (_Float16)(f0 - (float)h0);
            _Float16 h1 = (_Float16)f1; A11[j] = h1; A21[j] = (_Float16)(f1 - (float)h1);
        }
    }

    // ---- fp32 x-projection weights + bias for C rows 16wv + 4q + r ----
    const int r0 = 16 * wv + 4 * q;
    float wih[4][4], bias[4];
    #pragma unroll
    for (int r = 0; r < 4; ++r) {
        bias[r] = b_ih[r0 + r] + b_hh[r0 + r];
        #pragma unroll
        for (int i = 0; i < ISZ; ++i) wih[r][i] = W_ih[(r0 + r) * ISZ + i];
    }

    // ---- per-lane x pipeline, depth 3; xp for step T computed during step T-1 ----
    const float* xrow = x + (size_t)(blk0 + n) * SEQ_T * ISZ;
    float4v xc  = *(const float4v*)(xrow);            // x(0)
    float4v xn1 = *(const float4v*)(xrow + ISZ);      // x(1)
    float4v xn2 = *(const float4v*)(xrow + 2 * ISZ);  // x(2)

    float p0 = bias[0], p1 = bias[1], p2 = bias[2], p3 = bias[3];
    #pragma unroll
    for (int i = 0; i < ISZ; ++i) {
        p0 = fmaf(xc[i], wih[0][i], p0);
        p1 = fmaf(xc[i], wih[1][i], p1);
        p2 = fmaf(xc[i], wih[2][i], p2);
        p3 = fmaf(xc[i], wih[3][i], p3);
    }

    const int gw = 2 * wv + (q >> 1);
    const int j0 = 4 * (q & 1);

    float hl0 = 0.f, hl1 = 0.f, hl2 = 0.f, hl3 = 0.f;

    __syncthreads();   // zero-init visible (prologue: full drain fine)

#define MFMA16(A, B, C) __builtin_amdgcn_mfma_f32_16x16x32_f16((A), (B), (C), 0, 0, 0)
#define RNN_STEP(RB, WB, T)                                                    \
    {                                                                          \
        int tn = (T) + 3; if (tn > SEQ_T - 1) tn = SEQ_T - 1;                  \
        const float4v xf = *(const float4v*)(xrow + (size_t)tn * ISZ);         \
        half8 B10 = *(const half8*)&hterm[ch][RB][0][    q][n][0];             \
        half8 B11 = *(const half8*)&hterm[ch][RB][0][4 + q][n][0];             \
        half8 B20 = *(const half8*)&hterm[ch][RB][1][    q][n][0];             \
        half8 B21 = *(const half8*)&hterm[ch][RB][1][4 + q][n][0];             \
        float4v accA = {p0, p1, p2, p3};                                       \
        float4v accB = {0.f, 0.f, 0.f, 0.f};                                   \
        accA = MFMA16(A10, B10, accA);  accB = MFMA16(A11, B11, accB);         \
        accA = MFMA16(A10, B20, accA);  accB = MFMA16(A11, B21, accB);         \
        accA = MFMA16(A20, B10, accA);  accB = MFMA16(A21, B11, accB);         \
        hl0 = fast_tanh(accA[0] + accB[0]); hl1 = fast_tanh(accA[1] + accB[1]);\
        hl2 = fast_tanh(accA[2] + accB[2]); hl3 = fast_tanh(accA[3] + accB[3]);\
        half2v hi01 = pk_f16(hl0, hl1), hi23 = pk_f16(hl2, hl3);               \
        float s0 = hl0 - (float)hi01[0], s1 = hl1 - (float)hi01[1];            \
        float s2 = hl2 - (float)hi23[0], s3 = hl3 - (float)hi23[1];            \
        half2v lo01 = pk_f16(s0, s1), lo23 = pk_f16(s2, s3);                   \
        uint2v whi = { __builtin_bit_cast(unsigned int, hi01),                 \
                       __builtin_bit_cast(unsigned int, hi23) };               \
        uint2v wlo = { __builtin_bit_cast(unsigned int, lo01),                 \
                       __builtin_bit_cast(unsigned int, lo23) };               \
        *(uint2v*)&hterm[ch][WB][0][gw][n][j0] = whi;                          \
        *(uint2v*)&hterm[ch][WB][1][gw][n][j0] = wlo;                          \
        /* xp for step T+1: off the critical path, overlaps the barrier wait */\
        p0 = bias[0]; p1 = bias[1]; p2 = bias[2]; p3 = bias[3];                \
        _Pragma("unroll")                                                      \
        for (int i = 0; i < ISZ; ++i) {                                        \
            p0 = fmaf(xn1[i], wih[0][i], p0);                                  \
            p1 = fmaf(xn1[i], wih[1][i], p1);                                  \
            p2 = fmaf(xn1[i], wih[2][i], p2);                                  \
            p3 = fmaf(xn1[i], wih[3][i], p3);                                  \
        }                                                                      \
        xn1 = xn2; xn2 = xf;                                                   \
        LDS_BARRIER();                                                         \
    }

    for (int t = 0; t < SEQ_T; t += 2) {
        RNN_STEP(0, 1, t)
        RNN_STEP(1, 0, t + 1)
    }
#undef RNN_STEP
#undef MFMA16

    // ---- fc epilogue on fp32 final h (in registers) ----
    {
        float4v hv = {hl0, hl1, hl2, hl3};
        *(float4v*)&hf[ch][n][16 * wv + 4 * q] = hv;
    }
    __syncthreads();
    for (int it = ctid; it < RPB * OSZ; it += 256) {
        const int b = it / OSZ;
        const int o = it - b * OSZ;
        const float* wo = fc_W + o * HID;
        float acc = fc_b[o];
        #pragma unroll
        for (int j = 0; j < HID; ++j)
            acc = fmaf(hf[ch][b][j], wo[j], acc);
        out[(size_t)(blk0 + b) * OSZ + o] = acc;
    }
}

extern "C" void kernel_launch(void* const* d_in, const int* in_sizes, int n_in,
                              void* d_out, int out_size, void* d_ws, size_t ws_size,
                              hipStream_t stream) {
    const float* x    = (const float*)d_in[0];
    const float* W_ih = (const float*)d_in[1];
    const float* W_hh = (const float*)d_in[2];
    const float* b_ih = (const float*)d_in[3];
    const float* b_hh = (const float*)d_in[4];
    const float* fc_W = (const float*)d_in[5];
    const float* fc_b = (const float*)d_in[6];
    float* out = (float*)d_out;

    rnn_f16x2_kernel<<<BATCH / (RPB * NCH), 512, 0, stream>>>(
        x, W_ih, W_hh, b_ih, b_hh, fc_W, fc_b, out);
}

// Round 4
// 216.499 us; speedup vs baseline: 1.3507x; 1.3507x over previous
//
#include <hip/hip_runtime.h>
#include <math.h>

#define BATCH 4096
#define SEQ_T 512
#define ISZ   4
#define HID   64
#define OSZ   40
#define RPB   16     // batch rows per block (MFMA N); grid = 256 = 1 block/CU

typedef __attribute__((ext_vector_type(8))) _Float16     half8;
typedef __attribute__((ext_vector_type(2))) _Float16     half2v;
typedef __attribute__((ext_vector_type(4))) float        float4v;
typedef __attribute__((ext_vector_type(2))) unsigned int uint2v;

static __device__ __forceinline__ half2v pk_f16(float a, float b) {
    return __builtin_bit_cast(half2v, __builtin_amdgcn_cvt_pkrtz(a, b)); // v_cvt_pkrtz_f16_f32
}

// tanh(x) = 1 - 2/(exp2(x*2*log2e)+1); saturating, NaN-free
static __device__ __forceinline__ float fast_tanh(float x) {
    float e = __builtin_amdgcn_exp2f(x * 2.885390081777927f);
    return fmaf(-2.0f, __builtin_amdgcn_rcpf(e + 1.0f), 1.0f);
}

// LDS-only barrier: ds_writes drained (lgkmcnt), global x prefetches stay in flight.
#define LDS_BARRIER() asm volatile("s_waitcnt lgkmcnt(0)\n\ts_barrier" ::: "memory")

// Phase-split schedule (r2 post-mortem): per-update cost decomposes into
// ~580cy dependency chain (bar->ds_read->3-dep MFMA->tanh->pack->ds_write->bar)
// + ~250cy issue work. One chain per block, TWO wave-groups: group 0 computes
// even updates, group 1 odd updates. Dependent phases tile the timeline (no
// stall alignment, unlike r2's independent chains on one barrier); each group's
// issue (xp, tanh tail) hides under the other group's latency phase. Waves w
// and w+4 share a SIMD -> one active + one idle wave per SIMD at all times.
__global__ __launch_bounds__(512, 1)
void rnn_f16x2_kernel(const float* __restrict__ x,
                      const float* __restrict__ W_ih,
                      const float* __restrict__ W_hh,
                      const float* __restrict__ b_ih,
                      const float* __restrict__ b_hh,
                      const float* __restrict__ fc_W,
                      const float* __restrict__ fc_b,
                      float* __restrict__ out)
{
    // hterm[buf][tau][g][n][j] = h_tau[k=8g+j] for batch col n (B-fragment-native).
    // Reader lane(n,q): b128 at [tau][4c+q][n][0] -> 2-way bank alias (free).
    // Writer lane(n,q) wave wg: rows 16wg+4q+r -> g=2wg+(q>>1), j0=4(q&1): b64, 2-way.
    __shared__ __attribute__((aligned(16))) _Float16 hterm[2][2][8][16][8];
    __shared__ __attribute__((aligned(16))) float hf[16][68];

    const int tid  = threadIdx.x;
    const int grp  = tid >> 8;         // 0: even updates, 1: odd updates
    const int wg   = (tid >> 6) & 3;   // wave-in-group: M-slice of H
    const int lane = tid & 63;
    const int n    = lane & 15;        // A: row m; B/C/D: batch col n
    const int q    = lane >> 4;
    const int blk0 = blockIdx.x * RPB;

    // h(0) = 0: zero both buffers
    {
        unsigned int* p = (unsigned int*)hterm;
        #pragma unroll
        for (int i = tid; i < (int)(sizeof(hterm) / 4); i += 512) p[i] = 0u;
    }

    // ---- static A fragments: W_hh row 16wg+n, 2-term fp16 split, K-chunks c=0,1 ----
    half8 A10, A11, A20, A21;   // A1x = hi term, A2x = residual term
    {
        const float* wr = W_hh + (16 * wg + n) * HID;
        #pragma unroll
        for (int j = 0; j < 8; ++j) {
            float f0 = wr[     8 * q + j];
            float f1 = wr[32 + 8 * q + j];
            _Float16 h0 = (_Float16)f0; A10[j] = h0; A20[j] = (_Float16)(f0 - (float)h0);
            _Float16 h1 = (_Float16)f1; A11[j] = h1; A21[j] = (_Float16)(f1 - (float)h1);
        }
    }

    // ---- fp32 x-projection weights + bias for C rows 16wg + 4q + r ----
    const int r0 = 16 * wg + 4 * q;
    float wih[4][4], bias[4];
    #pragma unroll
    for (int r = 0; r < 4; ++r) {
        bias[r] = b_ih[r0 + r] + b_hh[r0 + r];
        #pragma unroll
        for (int i = 0; i < ISZ; ++i) wih[r][i] = W_ih[(r0 + r) * ISZ + i];
    }

    // ---- per-group x pipeline: this group's updates are u = grp, grp+2, ... ----
    const float* xrow = x + (size_t)(blk0 + n) * SEQ_T * ISZ;
    float4v x1 = *(const float4v*)(xrow + (size_t)(grp    ) * ISZ);
    float4v x2 = *(const float4v*)(xrow + (size_t)(grp + 2) * ISZ);
    float4v x3 = *(const float4v*)(xrow + (size_t)(grp + 4) * ISZ);
    int tnext = grp + 6;

    const int gw = 2 * wg + (q >> 1);
    const int j0 = 4 * (q & 1);

    float p0, p1, p2, p3;
    float hl0 = 0.f, hl1 = 0.f, hl2 = 0.f, hl3 = 0.f;

    __syncthreads();   // zero-init visible (prologue: full drain fine)

#define MFMA16(A, B, C) __builtin_amdgcn_mfma_f32_16x16x32_f16((A), (B), (C), 0, 0, 0)

#define XP_COMPUTE()                                                           \
    {                                                                          \
        p0 = bias[0]; p1 = bias[1]; p2 = bias[2]; p3 = bias[3];                \
        _Pragma("unroll")                                                      \
        for (int i = 0; i < ISZ; ++i) {                                        \
            p0 = fmaf(x1[i], wih[0][i], p0);                                   \
            p1 = fmaf(x1[i], wih[1][i], p1);                                   \
            p2 = fmaf(x1[i], wih[2][i], p2);                                   \
            p3 = fmaf(x1[i], wih[3][i], p3);                                   \
        }                                                                      \
    }

#define XSHIFT()                                                               \
    {                                                                          \
        int tn = tnext; if (tn > SEQ_T - 1) tn = SEQ_T - 1;                    \
        float4v xf = *(const float4v*)(xrow + (size_t)tn * ISZ);               \
        tnext += 2;                                                            \
        x1 = x2; x2 = x3; x3 = xf;                                             \
    }

#define ACTIVE_STEP(RB, WB)                                                    \
    {                                                                          \
        half8 B10 = *(const half8*)&hterm[RB][0][    q][n][0];                 \
        half8 B11 = *(const half8*)&hterm[RB][0][4 + q][n][0];                 \
        half8 B20 = *(const half8*)&hterm[RB][1][    q][n][0];                 \
        half8 B21 = *(const half8*)&hterm[RB][1][4 + q][n][0];                 \
        float4v accA = {p0, p1, p2, p3};                                       \
        float4v accB = {0.f, 0.f, 0.f, 0.f};                                   \
        accA = MFMA16(A10, B10, accA);  accB = MFMA16(A11, B11, accB);         \
        accA = MFMA16(A10, B20, accA);  accB = MFMA16(A11, B21, accB);         \
        accA = MFMA16(A20, B10, accA);  accB = MFMA16(A21, B11, accB);         \
        hl0 = fast_tanh(accA[0] + accB[0]); hl1 = fast_tanh(accA[1] + accB[1]);\
        hl2 = fast_tanh(accA[2] + accB[2]); hl3 = fast_tanh(accA[3] + accB[3]);\
        half2v hi01 = pk_f16(hl0, hl1), hi23 = pk_f16(hl2, hl3);               \
        float s0 = hl0 - (float)hi01[0], s1 = hl1 - (float)hi01[1];            \
        float s2 = hl2 - (float)hi23[0], s3 = hl3 - (float)hi23[1];            \
        half2v lo01 = pk_f16(s0, s1), lo23 = pk_f16(s2, s3);                   \
        uint2v whi = { __builtin_bit_cast(unsigned int, hi01),                 \
                       __builtin_bit_cast(unsigned int, hi23) };               \
        uint2v wlo = { __builtin_bit_cast(unsigned int, lo01),                 \
                       __builtin_bit_cast(unsigned int, lo23) };               \
        *(uint2v*)&hterm[WB][0][gw][n][j0] = whi;                              \
        *(uint2v*)&hterm[WB][1][gw][n][j0] = wlo;                              \
    }

    if (grp == 0) {
        // even updates: active in phase A, xp-precompute in phase B (idle)
        XP_COMPUTE(); XSHIFT();                  // xp for update 0
        for (int it = 0; it < SEQ_T / 2; ++it) {
            ACTIVE_STEP(0, 1);                   // update 2*it: buf0 -> buf1
            LDS_BARRIER();
            XP_COMPUTE(); XSHIFT();              // xp for update 2*it+2
            LDS_BARRIER();
        }
    } else {
        // odd updates: xp-precompute in phase A (idle), active in phase B
        for (int it = 0; it < SEQ_T / 2; ++it) {
            XP_COMPUTE(); XSHIFT();              // xp for update 2*it+1
            LDS_BARRIER();
            ACTIVE_STEP(1, 0);                   // update 2*it+1: buf1 -> buf0
            LDS_BARRIER();
        }
    }
#undef ACTIVE_STEP
#undef XSHIFT
#undef XP_COMPUTE
#undef MFMA16

    // ---- fc epilogue: final h (update 511) lives in group 1's registers ----
    if (grp == 1) {
        float4v hv = {hl0, hl1, hl2, hl3};
        *(float4v*)&hf[n][r0] = hv;
    }
    __syncthreads();
    for (int it = tid; it < RPB * OSZ; it += 512) {
        const int b = it / OSZ;
        const int o = it - b * OSZ;
        const float* wo = fc_W + o * HID;
        float acc = fc_b[o];
        #pragma unroll
        for (int j = 0; j < HID; ++j)
            acc = fmaf(hf[b][j], wo[j], acc);
        out[(size_t)(blk0 + b) * OSZ + o] = acc;
    }
}

extern "C" void kernel_launch(void* const* d_in, const int* in_sizes, int n_in,
                              void* d_out, int out_size, void* d_ws, size_t ws_size,
                              hipStream_t stream) {
    const float* x    = (const float*)d_in[0];
    const float* W_ih = (const float*)d_in[1];
    const float* W_hh = (const float*)d_in[2];
    const float* b_ih = (const float*)d_in[3];
    const float* b_hh = (const float*)d_in[4];
    const float* fc_W = (const float*)d_in[5];
    const float* fc_b = (const float*)d_in[6];
    float* out = (float*)d_out;

    rnn_f16x2_kernel<<<BATCH / RPB, 512, 0, stream>>>(
        x, W_ih, W_hh, b_ih, b_hh, fc_W, fc_b, out);
}